// Round 14
// baseline (328.390 us; speedup 1.0000x reference)
//
#include <hip/hip_runtime.h>
#include <stdint.h>

typedef unsigned short u16;

#define Bb 4
#define Hh 4
#define Tt 8
#define Cc 256
#define NP 196
#define Ss 1568                 // Tt*NP
#define SCALE_S 0.0252538136f   // 1/sqrt(1568)

typedef __attribute__((ext_vector_type(4))) float floatx4;
typedef __attribute__((ext_vector_type(8))) short shortx8;

__device__ __forceinline__ float bf2f(u16 u) {
    union { unsigned u; float f; } v; v.u = ((unsigned)u) << 16; return v.f;
}
__device__ __forceinline__ u16 f2bf(float f) {
    union { float f; unsigned u; } v; v.f = f;
    unsigned r = v.u + 0x7FFFu + ((v.u >> 16) & 1u);
    return (u16)(r >> 16);
}

// ---- K0: fp32 -> bf16 convert (weights) ----
__global__ __launch_bounds__(256) void k_convw(const float* __restrict__ src, u16* __restrict__ dst, int n) {
    int i = blockIdx.x * 256 + threadIdx.x;
    if (i < n) dst[i] = f2bf(src[i]);
}

// One BK=32 step: 4x4 grid of 16x16x32 bf16 MFMAs per wave (wave covers 64x64).
__device__ __forceinline__ void mfma_step(const u16* As, const u16* Bs, int lane,
                                          int wm, int wn, floatx4 acc[4][4]) {
    const int r15 = lane & 15;
    const int kq  = (lane >> 4) << 3;
    shortx8 a[4], b[4];
#pragma unroll
    for (int i = 0; i < 4; ++i)
        a[i] = *(const shortx8*)(As + (wm * 64 + i * 16 + r15) * 32 + kq);
#pragma unroll
    for (int j = 0; j < 4; ++j)
        b[j] = *(const shortx8*)(Bs + (wn * 64 + j * 16 + r15) * 32 + kq);
#pragma unroll
    for (int i = 0; i < 4; ++i)
#pragma unroll
        for (int j = 0; j < 4; ++j)
            acc[i][j] = __builtin_amdgcn_mfma_f32_16x16x32_bf16(a[i], b[j], acc[i][j], 0, 0, 0);
}

// C[m,n] = sum_k A[m,k]*B[n,k], 128x128 tile, software-pipelined register staging.
__device__ __forceinline__ void gemm_bt_core(const u16* A, const u16* Bm, int lda, int ldb,
                                             int mbase, int mlast, int nbase, int nlast,
                                             int KD, u16* As, u16* Bs, floatx4 acc[4][4]) {
    int tid = threadIdx.x;
    int lane = tid & 63, wave = tid >> 6, wm = wave >> 1, wn = wave & 1;
    int row0 = tid >> 2, row1 = 64 + (tid >> 2);
    int cole = (tid & 3) << 3;                 // 0,8,16,24
    int ga0 = mbase + row0; ga0 = ga0 <= mlast ? ga0 : mlast;
    int ga1 = mbase + row1; ga1 = ga1 <= mlast ? ga1 : mlast;
    int gb0 = nbase + row0; gb0 = gb0 <= nlast ? gb0 : nlast;
    int gb1 = nbase + row1; gb1 = gb1 <= nlast ? gb1 : nlast;
    const u16* pa0 = A  + (size_t)ga0 * lda + cole;
    const u16* pa1 = A  + (size_t)ga1 * lda + cole;
    const u16* pb0 = Bm + (size_t)gb0 * ldb + cole;
    const u16* pb1 = Bm + (size_t)gb1 * ldb + cole;
    shortx8 va0 = *(const shortx8*)(pa0);
    shortx8 va1 = *(const shortx8*)(pa1);
    shortx8 vb0 = *(const shortx8*)(pb0);
    shortx8 vb1 = *(const shortx8*)(pb1);
    for (int k0 = 0; k0 < KD; k0 += 32) {
        __syncthreads();                       // prior iter's LDS reads done
        *(shortx8*)(As + row0 * 32 + cole) = va0;
        *(shortx8*)(As + row1 * 32 + cole) = va1;
        *(shortx8*)(Bs + row0 * 32 + cole) = vb0;
        *(shortx8*)(Bs + row1 * 32 + cole) = vb1;
        int k1 = k0 + 32;
        if (k1 < KD) {                         // prefetch next tile (flies during MFMA)
            va0 = *(const shortx8*)(pa0 + k1);
            va1 = *(const shortx8*)(pa1 + k1);
            vb0 = *(const shortx8*)(pb0 + k1);
            vb1 = *(const shortx8*)(pb1 + k1);
        }
        __syncthreads();                       // staging visible
        mfma_step(As, Bs, lane, wm, wn, acc);
    }
}

// ---- K1: emb fp32 [B,T,C,N] -> x bf16 [B,S,C] ----
__global__ void k_transpose(const float* __restrict__ emb, u16* __restrict__ x) {
    __shared__ u16 tile[32][33];
    int bt = blockIdx.z;
    int c0 = blockIdx.y * 32, n0 = blockIdx.x * 32;
    const float* src = emb + (size_t)bt * Cc * NP;
#pragma unroll
    for (int rr = 0; rr < 32; rr += 8) {
        int c = c0 + threadIdx.y + rr;
        int n = n0 + threadIdx.x;
        u16 v = 0;
        if (n < NP) v = f2bf(src[(size_t)c * NP + n]);
        tile[threadIdx.y + rr][threadIdx.x] = v;
    }
    __syncthreads();
    int b = bt / Tt, t = bt % Tt;
    u16* dst = x + ((size_t)b * Ss + (size_t)t * NP) * Cc;
#pragma unroll
    for (int rr = 0; rr < 32; rr += 8) {
        int n = n0 + threadIdx.y + rr;
        int c = c0 + threadIdx.x;
        if (n < NP) dst[(size_t)n * Cc + c] = tile[threadIdx.x][threadIdx.y + rr];
    }
}

// ---- K2: QKV projections, all (qkv,b,h) parallel. V written transposed [C,S]. ----
__global__ __launch_bounds__(256) void k_qkv(const u16* __restrict__ x,
                                             const u16* __restrict__ Wq,
                                             const u16* __restrict__ Wk,
                                             const u16* __restrict__ Wv,
                                             u16* __restrict__ Q, u16* __restrict__ Kb,
                                             u16* __restrict__ Vt) {
    __shared__ __align__(16) u16 As[128 * 32], Bs[128 * 32];
    floatx4 acc[4][4];
#pragma unroll
    for (int i = 0; i < 4; ++i)
#pragma unroll
        for (int j = 0; j < 4; ++j) acc[i][j] = (floatx4)(0.f);
    int z = blockIdx.z;
    int qkv = z >> 4, bh = z & 15, b = bh >> 2, h = bh & 3;
    const u16* A = x + (size_t)b * Ss * Cc;
    const u16* W = (qkv == 0 ? Wq : (qkv == 1 ? Wk : Wv)) + (size_t)h * Cc * Cc;
    int mbase = blockIdx.y * 128, nbase = blockIdx.x * 128;
    gemm_bt_core(A, W, Cc, Cc, mbase, Ss - 1, nbase, Cc - 1, Cc, As, Bs, acc);

    int tid = threadIdx.x, lane = tid & 63, wave = tid >> 6, wm = wave >> 1, wn = wave & 1;
    int rq = (lane >> 4) << 2, cn = lane & 15;
    if (qkv < 2) {
        u16* out = (qkv == 0 ? Q : Kb) + (size_t)bh * Ss * Cc;
#pragma unroll
        for (int i = 0; i < 4; ++i) {
            int mb = mbase + wm * 64 + i * 16 + rq;
#pragma unroll
            for (int j = 0; j < 4; ++j) {
                int n = nbase + wn * 64 + j * 16 + cn;
#pragma unroll
                for (int r = 0; r < 4; ++r) {
                    int m = mb + r;
                    if (m < Ss) out[(size_t)m * Cc + n] = f2bf(acc[i][j][r]);
                }
            }
        }
    } else {
        u16* out = Vt + (size_t)bh * Cc * Ss;
#pragma unroll
        for (int i = 0; i < 4; ++i) {
            int m0 = mbase + wm * 64 + i * 16 + rq;
            if (m0 < Ss) {
#pragma unroll
                for (int j = 0; j < 4; ++j) {
                    int n = nbase + wn * 64 + j * 16 + cn;
                    ushort4 v;
                    v.x = f2bf(acc[i][j][0]); v.y = f2bf(acc[i][j][1]);
                    v.z = f2bf(acc[i][j][2]); v.w = f2bf(acc[i][j][3]);
                    *(ushort4*)(out + (size_t)n * Ss + m0) = v;
                }
            }
        }
    }
}

// ---- K3: Sc = (Q K^T)*SCALE_S -> bf16, + fp32 sum/sumsq atomics per (b,h) ----
__global__ __launch_bounds__(256) void k_scores(const u16* __restrict__ Q,
                                                const u16* __restrict__ Kb,
                                                u16* __restrict__ Sc, float* __restrict__ stats) {
    __shared__ __align__(16) u16 As[128 * 32], Bs[128 * 32];
    __shared__ float sred[8];
    floatx4 acc[4][4];
#pragma unroll
    for (int i = 0; i < 4; ++i)
#pragma unroll
        for (int j = 0; j < 4; ++j) acc[i][j] = (floatx4)(0.f);
    int bh = blockIdx.z;
    const u16* A  = Q  + (size_t)bh * Ss * Cc;
    const u16* Bm = Kb + (size_t)bh * Ss * Cc;
    int mbase = blockIdx.y * 128, nbase = blockIdx.x * 128;
    gemm_bt_core(A, Bm, Cc, Cc, mbase, Ss - 1, nbase, Ss - 1, Cc, As, Bs, acc);

    int tid = threadIdx.x, lane = tid & 63, wave = tid >> 6, wm = wave >> 1, wn = wave & 1;
    int rq = (lane >> 4) << 2, cn = lane & 15;
    u16* out = Sc + (size_t)bh * Ss * Ss;
    float lsum = 0.f, lsq = 0.f;
#pragma unroll
    for (int i = 0; i < 4; ++i) {
        int mb = mbase + wm * 64 + i * 16 + rq;
#pragma unroll
        for (int j = 0; j < 4; ++j) {
            int n = nbase + wn * 64 + j * 16 + cn;
            bool nv = n < Ss;
#pragma unroll
            for (int r = 0; r < 4; ++r) {
                int m = mb + r;
                if (nv && m < Ss) {
                    float v = acc[i][j][r] * SCALE_S;
                    out[(size_t)m * Ss + n] = f2bf(v);
                    lsum += v; lsq += v * v;
                }
            }
        }
    }
#pragma unroll
    for (int mk = 1; mk <= 32; mk <<= 1) { lsum += __shfl_xor(lsum, mk); lsq += __shfl_xor(lsq, mk); }
    if (lane == 0) { sred[wave] = lsum; sred[4 + wave] = lsq; }
    __syncthreads();
    if (tid == 0) atomicAdd(&stats[bh * 4 + 0], sred[0] + sred[1] + sred[2] + sred[3]);
    if (tid == 1) atomicAdd(&stats[bh * 4 + 1], sred[4] + sred[5] + sred[6] + sred[7]);
}

// ---- K4: finalize per-(b,h) mean / inv-std ----
__global__ void k_stats(float* __restrict__ stats) {
    int i = threadIdx.x;
    if (i < 16) {
        float inv  = 1.f / ((float)Ss * (float)Ss);
        float mean = stats[i * 4] * inv;
        float var  = stats[i * 4 + 1] * inv - mean * mean;
        var = fmaxf(var, 0.f);
        stats[i * 4 + 2] = mean;
        stats[i * 4 + 3] = rsqrtf(var + 1e-5f);
    }
}

// ---- K4b: per-row softmax denominators: rowsums[bh][s] = sum_t exp(norm(Sc[s,t])) ----
__global__ __launch_bounds__(256) void k_rowsum(const u16* __restrict__ Sc,
                                                const float* __restrict__ stats,
                                                float* __restrict__ rowsums) {
    __shared__ float red[4];
    int s = blockIdx.x, bh = blockIdx.y;
    int tid = threadIdx.x, lane = tid & 63, wave = tid >> 6;
    float istd = stats[bh * 4 + 3];
    float aa = istd * 1.44269504f;
    float bb = -stats[bh * 4 + 2] * aa;
    const u16* srow = Sc + ((size_t)bh * Ss + s) * Ss;
    float part = 0.f;
#pragma unroll
    for (int rep = 0; rep < 7; ++rep) {
        int t = tid + rep * 256;
        if (t < Ss) part += exp2f(bf2f(srow[t]) * aa + bb);
    }
#pragma unroll
    for (int mk = 1; mk <= 32; mk <<= 1) part += __shfl_xor(part, mk);
    if (lane == 0) red[wave] = part;
    __syncthreads();
    if (tid == 0) rowsums[(size_t)bh * Ss + s] = red[0] + red[1] + red[2] + red[3];
}

// ---- K5: PV with 64x256 block tile (waves 1x4), K-split x4, head-mean fused.
// Each A-row's exp computed ONCE (full C-width per block). ----
__global__ __launch_bounds__(256) void k_pv(const u16* __restrict__ Sc,
                                            const u16* __restrict__ Vt,
                                            const float* __restrict__ stats,
                                            const float* __restrict__ rowsums,
                                            float* __restrict__ ctxm) {
    __shared__ __align__(16) u16 As[64 * 32], Bs[256 * 32];
    floatx4 acc[4][4];
#pragma unroll
    for (int i = 0; i < 4; ++i)
#pragma unroll
        for (int j = 0; j < 4; ++j) acc[i][j] = (floatx4)(0.f);
    int z = blockIdx.z;
    int bh = z >> 2, split = z & 3;
    int mbase = blockIdx.x * 64;
    float istd = stats[bh * 4 + 3];
    float aa = istd * 1.44269504f;
    float bb = -stats[bh * 4 + 2] * aa;
    const u16* A  = Sc + (size_t)bh * Ss * Ss;   // [S][S]
    const u16* Bm = Vt + (size_t)bh * Cc * Ss;   // [C][S]
    int tid = threadIdx.x, lane = tid & 63, wave = tid >> 6;
    int row  = tid >> 2;                          // 0..63
    int cole = (tid & 3) << 3;                    // 0,8,16,24
    int ga = mbase + row; ga = ga <= Ss - 1 ? ga : Ss - 1;
    const u16* pa = A + (size_t)ga * Ss + cole;
    const u16* pb0 = Bm + (size_t)(row)       * Ss + cole;
    const u16* pb1 = Bm + (size_t)(row + 64)  * Ss + cole;
    const u16* pb2 = Bm + (size_t)(row + 128) * Ss + cole;
    const u16* pb3 = Bm + (size_t)(row + 192) * Ss + cole;
    // K-slice: 49 tiles of 32 split 12/12/12/13
    int t0 = ((49 * split) / 4) * 32;
    int t1 = ((49 * (split + 1)) / 4) * 32;
    shortx8 va  = *(const shortx8*)(pa + t0);
    shortx8 vb0 = *(const shortx8*)(pb0 + t0);
    shortx8 vb1 = *(const shortx8*)(pb1 + t0);
    shortx8 vb2 = *(const shortx8*)(pb2 + t0);
    shortx8 vb3 = *(const shortx8*)(pb3 + t0);

    for (int k0 = t0; k0 < t1; k0 += 32) {
        shortx8 o;
#pragma unroll
        for (int e = 0; e < 8; ++e) {
            float f = bf2f((u16)va[e]);
            o[e] = (short)f2bf(exp2f(f * aa + bb));
        }
        __syncthreads();                       // prior iter's LDS reads done
        *(shortx8*)(As + row * 32 + cole) = o;
        *(shortx8*)(Bs + (row)       * 32 + cole) = vb0;
        *(shortx8*)(Bs + (row + 64)  * 32 + cole) = vb1;
        *(shortx8*)(Bs + (row + 128) * 32 + cole) = vb2;
        *(shortx8*)(Bs + (row + 192) * 32 + cole) = vb3;
        int k1 = k0 + 32;
        if (k1 < t1) {                         // prefetch (flies during MFMA)
            va  = *(const shortx8*)(pa + k1);
            vb0 = *(const shortx8*)(pb0 + k1);
            vb1 = *(const shortx8*)(pb1 + k1);
            vb2 = *(const shortx8*)(pb2 + k1);
            vb3 = *(const shortx8*)(pb3 + k1);
        }
        __syncthreads();                       // staging visible
        mfma_step(As, Bs, lane, 0, wave, acc); // wm=0 (64 rows), wn=wave (4x64 cols)
    }

    // epilogue: ctxm[b,m,n] += 0.25 * acc / rowsum[m]
    int b = bh >> 2;
    float* outp = ctxm + (size_t)b * Ss * Cc;
    const float* rsb = rowsums + (size_t)bh * Ss;
    int rq = (lane >> 4) << 2, cn = lane & 15;
#pragma unroll
    for (int i = 0; i < 4; ++i) {
        int ml = i * 16 + rq;
#pragma unroll
        for (int r = 0; r < 4; ++r) {
            int m = mbase + ml + r;
            if (m < Ss) {
                float invs = 0.25f / rsb[m];
#pragma unroll
                for (int j = 0; j < 4; ++j) {
                    int n = wave * 64 + j * 16 + cn;
                    atomicAdd(&outp[(size_t)m * Cc + n], acc[i][j][r] * invs);
                }
            }
        }
    }
}

// ---- K6: O = ctxm(fp32) @ Wo^T -> fp32 d_out (flat [B,S,C] == [B,T,C,N]) ----
__global__ __launch_bounds__(256) void k_out(const float* __restrict__ ctxm,
                                             const u16* __restrict__ Wo, float* __restrict__ out) {
    __shared__ __align__(16) u16 As[128 * 32], Bs[128 * 32];
    floatx4 acc[4][4];
#pragma unroll
    for (int i = 0; i < 4; ++i)
#pragma unroll
        for (int j = 0; j < 4; ++j) acc[i][j] = (floatx4)(0.f);
    int b = blockIdx.z;
    const float* A = ctxm + (size_t)b * Ss * Cc;
    int mbase = blockIdx.y * 128, nbase = blockIdx.x * 128;
    int tid = threadIdx.x, lane = tid & 63, wave = tid >> 6, wm = wave >> 1, wn = wave & 1;
    int row0 = tid >> 2, row1 = 64 + (tid >> 2);
    int cole = (tid & 3) << 3;
    int ga0 = mbase + row0; ga0 = ga0 <= Ss - 1 ? ga0 : Ss - 1;
    int ga1 = mbase + row1; ga1 = ga1 <= Ss - 1 ? ga1 : Ss - 1;
    const float* pa0 = A + (size_t)ga0 * Cc + cole;
    const float* pa1 = A + (size_t)ga1 * Cc + cole;
    const u16* pb0 = Wo + (size_t)(nbase + row0 <= Cc - 1 ? nbase + row0 : Cc - 1) * Cc + cole;
    const u16* pb1 = Wo + (size_t)(nbase + row1 <= Cc - 1 ? nbase + row1 : Cc - 1) * Cc + cole;
    float4 a00 = *(const float4*)(pa0), a01 = *(const float4*)(pa0 + 4);
    float4 a10 = *(const float4*)(pa1), a11 = *(const float4*)(pa1 + 4);
    shortx8 vb0 = *(const shortx8*)(pb0);
    shortx8 vb1 = *(const shortx8*)(pb1);
    for (int k0 = 0; k0 < Cc; k0 += 32) {
        shortx8 o0, o1;
        o0[0] = (short)f2bf(a00.x); o0[1] = (short)f2bf(a00.y); o0[2] = (short)f2bf(a00.z); o0[3] = (short)f2bf(a00.w);
        o0[4] = (short)f2bf(a01.x); o0[5] = (short)f2bf(a01.y); o0[6] = (short)f2bf(a01.z); o0[7] = (short)f2bf(a01.w);
        o1[0] = (short)f2bf(a10.x); o1[1] = (short)f2bf(a10.y); o1[2] = (short)f2bf(a10.z); o1[3] = (short)f2bf(a10.w);
        o1[4] = (short)f2bf(a11.x); o1[5] = (short)f2bf(a11.y); o1[6] = (short)f2bf(a11.z); o1[7] = (short)f2bf(a11.w);
        __syncthreads();
        *(shortx8*)(As + row0 * 32 + cole) = o0;
        *(shortx8*)(As + row1 * 32 + cole) = o1;
        *(shortx8*)(Bs + row0 * 32 + cole) = vb0;
        *(shortx8*)(Bs + row1 * 32 + cole) = vb1;
        int k1 = k0 + 32;
        if (k1 < Cc) {
            a00 = *(const float4*)(pa0 + k1); a01 = *(const float4*)(pa0 + k1 + 4);
            a10 = *(const float4*)(pa1 + k1); a11 = *(const float4*)(pa1 + k1 + 4);
            vb0 = *(const shortx8*)(pb0 + k1);
            vb1 = *(const shortx8*)(pb1 + k1);
        }
        __syncthreads();
        mfma_step(As, Bs, lane, wm, wn, acc);
    }
    int rq = (lane >> 4) << 2, cn = lane & 15;
    float* o = out + (size_t)b * Ss * Cc;
#pragma unroll
    for (int i = 0; i < 4; ++i) {
        int mb = mbase + wm * 64 + i * 16 + rq;
#pragma unroll
        for (int j = 0; j < 4; ++j) {
            int n = nbase + wn * 64 + j * 16 + cn;
#pragma unroll
            for (int r = 0; r < 4; ++r) {
                int m = mb + r;
                if (m < Ss) o[(size_t)m * Cc + n] = acc[i][j][r];   // fp32 store
            }
        }
    }
}

extern "C" void kernel_launch(void* const* d_in, const int* in_sizes, int n_in,
                              void* d_out, int out_size, void* d_ws, size_t ws_size,
                              hipStream_t stream) {
    const float* emb = (const float*)d_in[0];
    float* out = (float*)d_out;

    char* ws = (char*)d_ws;
    size_t off = 0;
    auto alloc = [&](size_t bytes) -> void* {
        void* p = ws + off;
        off = (off + bytes + 255) & ~(size_t)255;
        return p;
    };
    // Total ~122.7 MiB
    float* stats = (float*)alloc(16 * 4 * sizeof(float));
    float* rowsums = (float*)alloc((size_t)16 * Ss * sizeof(float));  // 100 KiB
    u16* Wqc  = (u16*)alloc((size_t)Hh * Cc * Cc * 2);
    u16* Wkc  = (u16*)alloc((size_t)Hh * Cc * Cc * 2);
    u16* Wvc  = (u16*)alloc((size_t)Hh * Cc * Cc * 2);
    u16* Woc  = (u16*)alloc((size_t)Cc * Cc * 2);
    u16* x    = (u16*)alloc((size_t)Bb * Ss * Cc * 2);            // 3.1 MiB
    u16* Q    = (u16*)alloc((size_t)Bb * Hh * Ss * Cc * 2);       // 12.25 MiB
    u16* Kb   = (u16*)alloc((size_t)Bb * Hh * Ss * Cc * 2);       // 12.25 MiB
    u16* Vt   = (u16*)alloc((size_t)Bb * Hh * Ss * Cc * 2);       // 12.25 MiB ([C,S])
    float* ctxm = (float*)alloc((size_t)Bb * Ss * Cc * 4);        // 6.1 MiB fp32 head-mean accum
    u16* Sc   = (u16*)alloc((size_t)Bb * Hh * Ss * Ss * 2);       // 75.0 MiB

    hipMemsetAsync(stats, 0, 16 * 4 * sizeof(float), stream);
    hipMemsetAsync(ctxm, 0, (size_t)Bb * Ss * Cc * 4, stream);

    k_convw<<<dim3(1024), dim3(256), 0, stream>>>((const float*)d_in[1], Wqc, Hh * Cc * Cc);
    k_convw<<<dim3(1024), dim3(256), 0, stream>>>((const float*)d_in[2], Wkc, Hh * Cc * Cc);
    k_convw<<<dim3(1024), dim3(256), 0, stream>>>((const float*)d_in[3], Wvc, Hh * Cc * Cc);
    k_convw<<<dim3(256),  dim3(256), 0, stream>>>((const float*)d_in[4], Woc, Cc * Cc);

    k_transpose<<<dim3(7, 8, 32), dim3(32, 8), 0, stream>>>(emb, x);
    k_qkv<<<dim3(2, 13, 48), dim3(256), 0, stream>>>(x, Wqc, Wkc, Wvc, Q, Kb, Vt);
    k_scores<<<dim3(13, 13, 16), dim3(256), 0, stream>>>(Q, Kb, Sc, stats);
    k_stats<<<dim3(1), dim3(64), 0, stream>>>(stats);
    k_rowsum<<<dim3(Ss, 16), dim3(256), 0, stream>>>(Sc, stats, rowsums);
    k_pv<<<dim3(25, 1, 64), dim3(256), 0, stream>>>(Sc, Vt, stats, rowsums, ctxm);
    k_out<<<dim3(2, 13, 4), dim3(256), 0, stream>>>(ctxm, Woc, out);
}

// Round 15
// 247.166 us; speedup vs baseline: 1.3286x; 1.3286x over previous
//
#include <hip/hip_runtime.h>
#include <stdint.h>

typedef unsigned short u16;

#define Bb 4
#define Hh 4
#define Tt 8
#define Cc 256
#define NP 196
#define Ss 1568                 // Tt*NP
#define SCALE_S 0.0252538136f   // 1/sqrt(1568)
#define LST 40                  // LDS row stride (elems): 80B = 20-bank stride -> 2-way max (free)

typedef __attribute__((ext_vector_type(4))) float floatx4;
typedef __attribute__((ext_vector_type(8))) short shortx8;

__device__ __forceinline__ float bf2f(u16 u) {
    union { unsigned u; float f; } v; v.u = ((unsigned)u) << 16; return v.f;
}
__device__ __forceinline__ u16 f2bf(float f) {
    union { float f; unsigned u; } v; v.f = f;
    unsigned r = v.u + 0x7FFFu + ((v.u >> 16) & 1u);
    return (u16)(r >> 16);
}

// ---- K0: all weights fp32 -> one bf16 buffer [Wq|Wk|Wv|Wo] ----
__global__ __launch_bounds__(256) void k_convall(const float* __restrict__ Wq,
                                                 const float* __restrict__ Wk,
                                                 const float* __restrict__ Wv,
                                                 const float* __restrict__ Wo,
                                                 u16* __restrict__ dst) {
    const int NW = Hh * Cc * Cc;     // 262144
    int i = blockIdx.x * 256 + threadIdx.x;
    float v;
    if (i < NW) v = Wq[i];
    else if (i < 2 * NW) v = Wk[i - NW];
    else if (i < 3 * NW) v = Wv[i - 2 * NW];
    else if (i < 3 * NW + Cc * Cc) v = Wo[i - 3 * NW];
    else return;
    dst[i] = f2bf(v);
}

// One BK=32 step: 4x4 grid of 16x16x32 bf16 MFMAs per wave (wave covers 64x64).
__device__ __forceinline__ void mfma_step(const u16* As, const u16* Bs, int lane,
                                          int wm, int wn, floatx4 acc[4][4]) {
    const int r15 = lane & 15;
    const int kq  = (lane >> 4) << 3;
    shortx8 a[4], b[4];
#pragma unroll
    for (int i = 0; i < 4; ++i)
        a[i] = *(const shortx8*)(As + (wm * 64 + i * 16 + r15) * LST + kq);
#pragma unroll
    for (int j = 0; j < 4; ++j)
        b[j] = *(const shortx8*)(Bs + (wn * 64 + j * 16 + r15) * LST + kq);
#pragma unroll
    for (int i = 0; i < 4; ++i)
#pragma unroll
        for (int j = 0; j < 4; ++j)
            acc[i][j] = __builtin_amdgcn_mfma_f32_16x16x32_bf16(a[i], b[j], acc[i][j], 0, 0, 0);
}

// C[m,n] = sum_k A[m,k]*B[n,k], 128x128 tile, depth-2 prefetch (two reg sets, tile pairs).
__device__ __forceinline__ void gemm_bt_core(const u16* A, const u16* Bm, int lda, int ldb,
                                             int mbase, int mlast, int nbase, int nlast,
                                             int KD, u16* As, u16* Bs, floatx4 acc[4][4]) {
    int tid = threadIdx.x;
    int lane = tid & 63, wave = tid >> 6, wm = wave >> 1, wn = wave & 1;
    int row0 = tid >> 2, row1 = 64 + row0;
    int cole = (tid & 3) << 3;                 // 0,8,16,24
    int ga0 = mbase + row0; ga0 = ga0 <= mlast ? ga0 : mlast;
    int ga1 = mbase + row1; ga1 = ga1 <= mlast ? ga1 : mlast;
    int gb0 = nbase + row0; gb0 = gb0 <= nlast ? gb0 : nlast;
    int gb1 = nbase + row1; gb1 = gb1 <= nlast ? gb1 : nlast;
    const u16* pa0 = A  + (size_t)ga0 * lda + cole;
    const u16* pa1 = A  + (size_t)ga1 * lda + cole;
    const u16* pb0 = Bm + (size_t)gb0 * ldb + cole;
    const u16* pb1 = Bm + (size_t)gb1 * ldb + cole;
    // set X = even tiles (k%64==0), set Y = odd tiles
    shortx8 xa0 = *(const shortx8*)(pa0),      xa1 = *(const shortx8*)(pa1);
    shortx8 xb0 = *(const shortx8*)(pb0),      xb1 = *(const shortx8*)(pb1);
    shortx8 ya0 = *(const shortx8*)(pa0 + 32), ya1 = *(const shortx8*)(pa1 + 32);
    shortx8 yb0 = *(const shortx8*)(pb0 + 32), yb1 = *(const shortx8*)(pb1 + 32);
    for (int k0 = 0; k0 < KD; k0 += 64) {
        __syncthreads();
        *(shortx8*)(As + row0 * LST + cole) = xa0;
        *(shortx8*)(As + row1 * LST + cole) = xa1;
        *(shortx8*)(Bs + row0 * LST + cole) = xb0;
        *(shortx8*)(Bs + row1 * LST + cole) = xb1;
        int kp = k0 + 64;
        if (kp < KD) {
            xa0 = *(const shortx8*)(pa0 + kp); xa1 = *(const shortx8*)(pa1 + kp);
            xb0 = *(const shortx8*)(pb0 + kp); xb1 = *(const shortx8*)(pb1 + kp);
        }
        __syncthreads();
        mfma_step(As, Bs, lane, wm, wn, acc);
        if (k0 + 32 < KD) {
            __syncthreads();
            *(shortx8*)(As + row0 * LST + cole) = ya0;
            *(shortx8*)(As + row1 * LST + cole) = ya1;
            *(shortx8*)(Bs + row0 * LST + cole) = yb0;
            *(shortx8*)(Bs + row1 * LST + cole) = yb1;
            int kq2 = k0 + 96;
            if (kq2 < KD) {
                ya0 = *(const shortx8*)(pa0 + kq2); ya1 = *(const shortx8*)(pa1 + kq2);
                yb0 = *(const shortx8*)(pb0 + kq2); yb1 = *(const shortx8*)(pb1 + kq2);
            }
            __syncthreads();
            mfma_step(As, Bs, lane, wm, wn, acc);
        }
    }
}

// ---- K1: emb fp32 [B,T,C,N] -> x bf16 [B,S,C] ----
__global__ void k_transpose(const float* __restrict__ emb, u16* __restrict__ x) {
    __shared__ u16 tile[32][33];
    int bt = blockIdx.z;
    int c0 = blockIdx.y * 32, n0 = blockIdx.x * 32;
    const float* src = emb + (size_t)bt * Cc * NP;
#pragma unroll
    for (int rr = 0; rr < 32; rr += 8) {
        int c = c0 + threadIdx.y + rr;
        int n = n0 + threadIdx.x;
        u16 v = 0;
        if (n < NP) v = f2bf(src[(size_t)c * NP + n]);
        tile[threadIdx.y + rr][threadIdx.x] = v;
    }
    __syncthreads();
    int b = bt / Tt, t = bt % Tt;
    u16* dst = x + ((size_t)b * Ss + (size_t)t * NP) * Cc;
#pragma unroll
    for (int rr = 0; rr < 32; rr += 8) {
        int n = n0 + threadIdx.y + rr;
        int c = c0 + threadIdx.x;
        if (n < NP) dst[(size_t)n * Cc + c] = tile[threadIdx.x][threadIdx.y + rr];
    }
}

// ---- K2: QKV projections. V written transposed [C,S]. ----
__global__ __launch_bounds__(256) void k_qkv(const u16* __restrict__ x,
                                             const u16* __restrict__ Wall,
                                             u16* __restrict__ Q, u16* __restrict__ Kb,
                                             u16* __restrict__ Vt) {
    __shared__ __align__(16) u16 As[128 * LST], Bs[128 * LST];
    floatx4 acc[4][4];
#pragma unroll
    for (int i = 0; i < 4; ++i)
#pragma unroll
        for (int j = 0; j < 4; ++j) acc[i][j] = (floatx4)(0.f);
    int z = blockIdx.z;
    int qkv = z >> 4, bh = z & 15, b = bh >> 2, h = bh & 3;
    const u16* A = x + (size_t)b * Ss * Cc;
    const u16* W = Wall + (size_t)qkv * Hh * Cc * Cc + (size_t)h * Cc * Cc;
    int mbase = blockIdx.y * 128, nbase = blockIdx.x * 128;
    gemm_bt_core(A, W, Cc, Cc, mbase, Ss - 1, nbase, Cc - 1, Cc, As, Bs, acc);

    int tid = threadIdx.x, lane = tid & 63, wave = tid >> 6, wm = wave >> 1, wn = wave & 1;
    int rq = (lane >> 4) << 2, cn = lane & 15;
    if (qkv < 2) {
        u16* out = (qkv == 0 ? Q : Kb) + (size_t)bh * Ss * Cc;
#pragma unroll
        for (int i = 0; i < 4; ++i) {
            int mb = mbase + wm * 64 + i * 16 + rq;
#pragma unroll
            for (int j = 0; j < 4; ++j) {
                int n = nbase + wn * 64 + j * 16 + cn;
#pragma unroll
                for (int r = 0; r < 4; ++r) {
                    int m = mb + r;
                    if (m < Ss) out[(size_t)m * Cc + n] = f2bf(acc[i][j][r]);
                }
            }
        }
    } else {
        u16* out = Vt + (size_t)bh * Cc * Ss;
#pragma unroll
        for (int i = 0; i < 4; ++i) {
            int m0 = mbase + wm * 64 + i * 16 + rq;
            if (m0 < Ss) {
#pragma unroll
                for (int j = 0; j < 4; ++j) {
                    int n = nbase + wn * 64 + j * 16 + cn;
                    ushort4 v;
                    v.x = f2bf(acc[i][j][0]); v.y = f2bf(acc[i][j][1]);
                    v.z = f2bf(acc[i][j][2]); v.w = f2bf(acc[i][j][3]);
                    *(ushort4*)(out + (size_t)n * Ss + m0) = v;
                }
            }
        }
    }
}

// ---- K3: Sc = (Q K^T)*SCALE_S -> bf16, + fp32 sum/sumsq atomics per (b,h) ----
__global__ __launch_bounds__(256) void k_scores(const u16* __restrict__ Q,
                                                const u16* __restrict__ Kb,
                                                u16* __restrict__ Sc, float* __restrict__ stats) {
    __shared__ __align__(16) u16 As[128 * LST], Bs[128 * LST];
    __shared__ float sred[8];
    floatx4 acc[4][4];
#pragma unroll
    for (int i = 0; i < 4; ++i)
#pragma unroll
        for (int j = 0; j < 4; ++j) acc[i][j] = (floatx4)(0.f);
    int bh = blockIdx.z;
    const u16* A  = Q  + (size_t)bh * Ss * Cc;
    const u16* Bm = Kb + (size_t)bh * Ss * Cc;
    int mbase = blockIdx.y * 128, nbase = blockIdx.x * 128;
    gemm_bt_core(A, Bm, Cc, Cc, mbase, Ss - 1, nbase, Ss - 1, Cc, As, Bs, acc);

    int tid = threadIdx.x, lane = tid & 63, wave = tid >> 6, wm = wave >> 1, wn = wave & 1;
    int rq = (lane >> 4) << 2, cn = lane & 15;
    u16* out = Sc + (size_t)bh * Ss * Ss;
    float lsum = 0.f, lsq = 0.f;
#pragma unroll
    for (int i = 0; i < 4; ++i) {
        int mb = mbase + wm * 64 + i * 16 + rq;
#pragma unroll
        for (int j = 0; j < 4; ++j) {
            int n = nbase + wn * 64 + j * 16 + cn;
            bool nv = n < Ss;
#pragma unroll
            for (int r = 0; r < 4; ++r) {
                int m = mb + r;
                if (nv && m < Ss) {
                    float v = acc[i][j][r] * SCALE_S;
                    out[(size_t)m * Ss + n] = f2bf(v);
                    lsum += v; lsq += v * v;
                }
            }
        }
    }
#pragma unroll
    for (int mk = 1; mk <= 32; mk <<= 1) { lsum += __shfl_xor(lsum, mk); lsq += __shfl_xor(lsq, mk); }
    if (lane == 0) { sred[wave] = lsum; sred[4 + wave] = lsq; }
    __syncthreads();
    if (tid == 0) atomicAdd(&stats[bh * 4 + 0], sred[0] + sred[1] + sred[2] + sred[3]);
    if (tid == 1) atomicAdd(&stats[bh * 4 + 1], sred[4] + sred[5] + sred[6] + sred[7]);
}

// ---- K5: softmax(norm(Sc)) @ V, depth-2 prefetch with exp AT LOAD TIME;
// stats finalized inline; head-mean fused via fp32 atomics (4 adds/elem). ----
__global__ __launch_bounds__(256) void k_pv(const u16* __restrict__ Sc,
                                            const u16* __restrict__ Vt,
                                            const float* __restrict__ stats,
                                            float* __restrict__ ctxm) {
    __shared__ __align__(16) u16 As[128 * LST], Bs[128 * LST];
    __shared__ float rs[128];
    floatx4 acc[4][4];
#pragma unroll
    for (int i = 0; i < 4; ++i)
#pragma unroll
        for (int j = 0; j < 4; ++j) acc[i][j] = (floatx4)(0.f);
    int bh = blockIdx.z;
    // inline stats finalize (was k_stats)
    float inv  = 1.f / ((float)Ss * (float)Ss);
    float mean = stats[bh * 4] * inv;
    float var  = fmaxf(stats[bh * 4 + 1] * inv - mean * mean, 0.f);
    float istd = rsqrtf(var + 1e-5f);
    float aa = istd * 1.44269504f;   // log2(e)*istd
    float bb = -mean * aa;
    const u16* A  = Sc + (size_t)bh * Ss * Ss;   // [S][S]
    const u16* Bm = Vt + (size_t)bh * Cc * Ss;   // [C][S]
    int mbase = blockIdx.y * 128, nbase = blockIdx.x * 128;
    int tid = threadIdx.x, lane = tid & 63, wave = tid >> 6, wm = wave >> 1, wn = wave & 1;
    int row0 = tid >> 2, row1 = 64 + row0;
    int cole = (tid & 3) << 3;
    int ga0 = mbase + row0; ga0 = ga0 <= Ss - 1 ? ga0 : Ss - 1;
    int ga1 = mbase + row1; ga1 = ga1 <= Ss - 1 ? ga1 : Ss - 1;
    const u16* pa0 = A + (size_t)ga0 * Ss + cole;
    const u16* pa1 = A + (size_t)ga1 * Ss + cole;
    const u16* pb0 = Bm + (size_t)(nbase + row0) * Ss + cole;
    const u16* pb1 = Bm + (size_t)(nbase + row1) * Ss + cole;
    float rsum0 = 0.f, rsum1 = 0.f;

    // load + exp in one step (keeps exp off the publish critical path)
    auto ldexp8 = [&](const u16* p, float& rsum) -> shortx8 {
        shortx8 v = *(const shortx8*)(p);
        shortx8 o;
        float s = 0.f;
#pragma unroll
        for (int e = 0; e < 8; ++e) {
            float ex = exp2f(bf2f((u16)v[e]) * aa + bb);
            s += ex; o[e] = (short)f2bf(ex);
        }
        rsum += s;
        return o;
    };

    // set X = tiles k%64==0, set Y = tiles k%64==32
    shortx8 xa0 = ldexp8(pa0, rsum0),      xa1 = ldexp8(pa1, rsum1);
    shortx8 xb0 = *(const shortx8*)(pb0),  xb1 = *(const shortx8*)(pb1);
    shortx8 ya0 = ldexp8(pa0 + 32, rsum0), ya1 = ldexp8(pa1 + 32, rsum1);
    shortx8 yb0 = *(const shortx8*)(pb0 + 32), yb1 = *(const shortx8*)(pb1 + 32);

    for (int k0 = 0; k0 < Ss; k0 += 64) {
        __syncthreads();
        *(shortx8*)(As + row0 * LST + cole) = xa0;
        *(shortx8*)(As + row1 * LST + cole) = xa1;
        *(shortx8*)(Bs + row0 * LST + cole) = xb0;
        *(shortx8*)(Bs + row1 * LST + cole) = xb1;
        int kp = k0 + 64;
        if (kp < Ss) {
            xa0 = ldexp8(pa0 + kp, rsum0); xa1 = ldexp8(pa1 + kp, rsum1);
            xb0 = *(const shortx8*)(pb0 + kp); xb1 = *(const shortx8*)(pb1 + kp);
        }
        __syncthreads();
        mfma_step(As, Bs, lane, wm, wn, acc);
        if (k0 + 32 < Ss) {
            __syncthreads();
            *(shortx8*)(As + row0 * LST + cole) = ya0;
            *(shortx8*)(As + row1 * LST + cole) = ya1;
            *(shortx8*)(Bs + row0 * LST + cole) = yb0;
            *(shortx8*)(Bs + row1 * LST + cole) = yb1;
            int kq2 = k0 + 96;
            if (kq2 < Ss) {
                ya0 = ldexp8(pa0 + kq2, rsum0); ya1 = ldexp8(pa1 + kq2, rsum1);
                yb0 = *(const shortx8*)(pb0 + kq2); yb1 = *(const shortx8*)(pb1 + kq2);
            }
            __syncthreads();
            mfma_step(As, Bs, lane, wm, wn, acc);
        }
    }
    rsum0 += __shfl_xor(rsum0, 1); rsum0 += __shfl_xor(rsum0, 2);
    rsum1 += __shfl_xor(rsum1, 1); rsum1 += __shfl_xor(rsum1, 2);
    __syncthreads();
    if ((tid & 3) == 0) { rs[tid >> 2] = rsum0; rs[64 + (tid >> 2)] = rsum1; }
    __syncthreads();

    // fused head-mean: ctxm[b,m,n] += 0.25 * acc / rowsum[m]
    int b = bh >> 2;
    float* outp = ctxm + (size_t)b * Ss * Cc;
    int rq = (lane >> 4) << 2, cn = lane & 15;
#pragma unroll
    for (int i = 0; i < 4; ++i) {
        int ml = wm * 64 + i * 16 + rq;
#pragma unroll
        for (int r = 0; r < 4; ++r) {
            int m = mbase + ml + r;
            if (m < Ss) {
                float invs = 0.25f / rs[ml + r];
#pragma unroll
                for (int j = 0; j < 4; ++j) {
                    int n = nbase + wn * 64 + j * 16 + cn;
                    atomicAdd(&outp[(size_t)m * Cc + n], acc[i][j][r] * invs);
                }
            }
        }
    }
}

// ---- K6: O = ctxm(fp32) @ Wo^T -> fp32 d_out (flat [B,S,C] == [B,T,C,N]) ----
__global__ __launch_bounds__(256) void k_out(const float* __restrict__ ctxm,
                                             const u16* __restrict__ Wo, float* __restrict__ out) {
    __shared__ __align__(16) u16 As[128 * LST], Bs[128 * LST];
    floatx4 acc[4][4];
#pragma unroll
    for (int i = 0; i < 4; ++i)
#pragma unroll
        for (int j = 0; j < 4; ++j) acc[i][j] = (floatx4)(0.f);
    int b = blockIdx.z;
    const float* A = ctxm + (size_t)b * Ss * Cc;
    int mbase = blockIdx.y * 128, nbase = blockIdx.x * 128;
    int tid = threadIdx.x, lane = tid & 63, wave = tid >> 6, wm = wave >> 1, wn = wave & 1;
    int row0 = tid >> 2, row1 = 64 + row0;
    int cole = (tid & 3) << 3;
    int ga0 = mbase + row0; ga0 = ga0 <= Ss - 1 ? ga0 : Ss - 1;
    int ga1 = mbase + row1; ga1 = ga1 <= Ss - 1 ? ga1 : Ss - 1;
    const float* pa0 = A + (size_t)ga0 * Cc + cole;
    const float* pa1 = A + (size_t)ga1 * Cc + cole;
    const u16* pb0 = Wo + (size_t)(nbase + row0 <= Cc - 1 ? nbase + row0 : Cc - 1) * Cc + cole;
    const u16* pb1 = Wo + (size_t)(nbase + row1 <= Cc - 1 ? nbase + row1 : Cc - 1) * Cc + cole;
    float4 a00 = *(const float4*)(pa0), a01 = *(const float4*)(pa0 + 4);
    float4 a10 = *(const float4*)(pa1), a11 = *(const float4*)(pa1 + 4);
    shortx8 vb0 = *(const shortx8*)(pb0);
    shortx8 vb1 = *(const shortx8*)(pb1);
    for (int k0 = 0; k0 < Cc; k0 += 32) {
        shortx8 o0, o1;
        o0[0] = (short)f2bf(a00.x); o0[1] = (short)f2bf(a00.y); o0[2] = (short)f2bf(a00.z); o0[3] = (short)f2bf(a00.w);
        o0[4] = (short)f2bf(a01.x); o0[5] = (short)f2bf(a01.y); o0[6] = (short)f2bf(a01.z); o0[7] = (short)f2bf(a01.w);
        o1[0] = (short)f2bf(a10.x); o1[1] = (short)f2bf(a10.y); o1[2] = (short)f2bf(a10.z); o1[3] = (short)f2bf(a10.w);
        o1[4] = (short)f2bf(a11.x); o1[5] = (short)f2bf(a11.y); o1[6] = (short)f2bf(a11.z); o1[7] = (short)f2bf(a11.w);
        __syncthreads();
        *(shortx8*)(As + row0 * LST + cole) = o0;
        *(shortx8*)(As + row1 * LST + cole) = o1;
        *(shortx8*)(Bs + row0 * LST + cole) = vb0;
        *(shortx8*)(Bs + row1 * LST + cole) = vb1;
        int k1 = k0 + 32;
        if (k1 < Cc) {
            a00 = *(const float4*)(pa0 + k1); a01 = *(const float4*)(pa0 + k1 + 4);
            a10 = *(const float4*)(pa1 + k1); a11 = *(const float4*)(pa1 + k1 + 4);
            vb0 = *(const shortx8*)(pb0 + k1);
            vb1 = *(const shortx8*)(pb1 + k1);
        }
        __syncthreads();
        mfma_step(As, Bs, lane, wm, wn, acc);
    }
    int rq = (lane >> 4) << 2, cn = lane & 15;
    float* o = out + (size_t)b * Ss * Cc;
#pragma unroll
    for (int i = 0; i < 4; ++i) {
        int mb = mbase + wm * 64 + i * 16 + rq;
#pragma unroll
        for (int j = 0; j < 4; ++j) {
            int n = nbase + wn * 64 + j * 16 + cn;
#pragma unroll
            for (int r = 0; r < 4; ++r) {
                int m = mb + r;
                if (m < Ss) o[(size_t)m * Cc + n] = acc[i][j][r];   // fp32 store
            }
        }
    }
}

extern "C" void kernel_launch(void* const* d_in, const int* in_sizes, int n_in,
                              void* d_out, int out_size, void* d_ws, size_t ws_size,
                              hipStream_t stream) {
    const float* emb = (const float*)d_in[0];
    float* out = (float*)d_out;

    char* ws = (char*)d_ws;
    size_t off = 0;
    auto alloc = [&](size_t bytes) -> void* {
        void* p = ws + off;
        off = (off + bytes + 255) & ~(size_t)255;
        return p;
    };
    // Total ~122.6 MiB
    float* stats = (float*)alloc(16 * 4 * sizeof(float));
    u16* Wall = (u16*)alloc((size_t)(3 * Hh + 1) * Cc * Cc * 2);  // [Wq|Wk|Wv|Wo] 1.66 MiB
    u16* x    = (u16*)alloc((size_t)Bb * Ss * Cc * 2);            // 3.1 MiB
    u16* Q    = (u16*)alloc((size_t)Bb * Hh * Ss * Cc * 2);       // 12.25 MiB
    u16* Kb   = (u16*)alloc((size_t)Bb * Hh * Ss * Cc * 2);       // 12.25 MiB
    u16* Vt   = (u16*)alloc((size_t)Bb * Hh * Ss * Cc * 2);       // 12.25 MiB ([C,S])
    float* ctxm = (float*)alloc((size_t)Bb * Ss * Cc * 4);        // 6.1 MiB fp32 head-mean accum
    u16* Sc   = (u16*)alloc((size_t)Bb * Hh * Ss * Ss * 2);       // 75.0 MiB
    u16* Woc  = Wall + (size_t)3 * Hh * Cc * Cc;

    hipMemsetAsync(stats, 0, 16 * 4 * sizeof(float), stream);
    hipMemsetAsync(ctxm, 0, (size_t)Bb * Ss * Cc * 4, stream);

    k_convall<<<dim3(3328), dim3(256), 0, stream>>>((const float*)d_in[1], (const float*)d_in[2],
                                                    (const float*)d_in[3], (const float*)d_in[4], Wall);
    k_transpose<<<dim3(7, 8, 32), dim3(32, 8), 0, stream>>>(emb, x);
    k_qkv<<<dim3(2, 13, 48), dim3(256), 0, stream>>>(x, Wall, Q, Kb, Vt);
    k_scores<<<dim3(13, 13, 16), dim3(256), 0, stream>>>(Q, Kb, Sc, stats);
    k_pv<<<dim3(2, 13, 16), dim3(256), 0, stream>>>(Sc, Vt, stats, ctxm);
    k_out<<<dim3(2, 13, 4), dim3(256), 0, stream>>>(ctxm, Woc, out);
}

// Round 16
// 243.492 us; speedup vs baseline: 1.3487x; 1.0151x over previous
//
#include <hip/hip_runtime.h>
#include <stdint.h>

typedef unsigned short u16;

#define Bb 4
#define Hh 4
#define Tt 8
#define Cc 256
#define NP 196
#define Ss 1568                 // Tt*NP
#define SCALE_S 0.0252538136f   // 1/sqrt(1568)
#define LST 32                  // LDS row stride: 32 measured better than 40 (R15: conflicts 2.6M->5.2M)

typedef __attribute__((ext_vector_type(4))) float floatx4;
typedef __attribute__((ext_vector_type(8))) short shortx8;

__device__ __forceinline__ float bf2f(u16 u) {
    union { unsigned u; float f; } v; v.u = ((unsigned)u) << 16; return v.f;
}
__device__ __forceinline__ u16 f2bf(float f) {
    union { float f; unsigned u; } v; v.f = f;
    unsigned r = v.u + 0x7FFFu + ((v.u >> 16) & 1u);
    return (u16)(r >> 16);
}

// ---- K0: all weights fp32 -> one bf16 buffer [Wq|Wk|Wv|Wo] ----
__global__ __launch_bounds__(256) void k_convall(const float* __restrict__ Wq,
                                                 const float* __restrict__ Wk,
                                                 const float* __restrict__ Wv,
                                                 const float* __restrict__ Wo,
                                                 u16* __restrict__ dst) {
    const int NW = Hh * Cc * Cc;     // 262144
    int i = blockIdx.x * 256 + threadIdx.x;
    float v;
    if (i < NW) v = Wq[i];
    else if (i < 2 * NW) v = Wk[i - NW];
    else if (i < 3 * NW) v = Wv[i - 2 * NW];
    else if (i < 3 * NW + Cc * Cc) v = Wo[i - 3 * NW];
    else return;
    dst[i] = f2bf(v);
}

// One BK=32 step: 4x4 grid of 16x16x32 bf16 MFMAs per wave (wave covers 64x64).
__device__ __forceinline__ void mfma_step(const u16* As, const u16* Bs, int lane,
                                          int wm, int wn, floatx4 acc[4][4]) {
    const int r15 = lane & 15;
    const int kq  = (lane >> 4) << 3;
    shortx8 a[4], b[4];
#pragma unroll
    for (int i = 0; i < 4; ++i)
        a[i] = *(const shortx8*)(As + (wm * 64 + i * 16 + r15) * LST + kq);
#pragma unroll
    for (int j = 0; j < 4; ++j)
        b[j] = *(const shortx8*)(Bs + (wn * 64 + j * 16 + r15) * LST + kq);
#pragma unroll
    for (int i = 0; i < 4; ++i)
#pragma unroll
        for (int j = 0; j < 4; ++j)
            acc[i][j] = __builtin_amdgcn_mfma_f32_16x16x32_bf16(a[i], b[j], acc[i][j], 0, 0, 0);
}

// C[m,n] = sum_k A[m,k]*B[n,k], 128x128 tile, depth-2 prefetch (two reg sets, tile pairs).
__device__ __forceinline__ void gemm_bt_core(const u16* A, const u16* Bm, int lda, int ldb,
                                             int mbase, int mlast, int nbase, int nlast,
                                             int KD, u16* As, u16* Bs, floatx4 acc[4][4]) {
    int tid = threadIdx.x;
    int lane = tid & 63, wave = tid >> 6, wm = wave >> 1, wn = wave & 1;
    int row0 = tid >> 2, row1 = 64 + row0;
    int cole = (tid & 3) << 3;                 // 0,8,16,24
    int ga0 = mbase + row0; ga0 = ga0 <= mlast ? ga0 : mlast;
    int ga1 = mbase + row1; ga1 = ga1 <= mlast ? ga1 : mlast;
    int gb0 = nbase + row0; gb0 = gb0 <= nlast ? gb0 : nlast;
    int gb1 = nbase + row1; gb1 = gb1 <= nlast ? gb1 : nlast;
    const u16* pa0 = A  + (size_t)ga0 * lda + cole;
    const u16* pa1 = A  + (size_t)ga1 * lda + cole;
    const u16* pb0 = Bm + (size_t)gb0 * ldb + cole;
    const u16* pb1 = Bm + (size_t)gb1 * ldb + cole;
    shortx8 xa0 = *(const shortx8*)(pa0),      xa1 = *(const shortx8*)(pa1);
    shortx8 xb0 = *(const shortx8*)(pb0),      xb1 = *(const shortx8*)(pb1);
    shortx8 ya0 = *(const shortx8*)(pa0 + 32), ya1 = *(const shortx8*)(pa1 + 32);
    shortx8 yb0 = *(const shortx8*)(pb0 + 32), yb1 = *(const shortx8*)(pb1 + 32);
    for (int k0 = 0; k0 < KD; k0 += 64) {
        __syncthreads();
        *(shortx8*)(As + row0 * LST + cole) = xa0;
        *(shortx8*)(As + row1 * LST + cole) = xa1;
        *(shortx8*)(Bs + row0 * LST + cole) = xb0;
        *(shortx8*)(Bs + row1 * LST + cole) = xb1;
        int kp = k0 + 64;
        if (kp < KD) {
            xa0 = *(const shortx8*)(pa0 + kp); xa1 = *(const shortx8*)(pa1 + kp);
            xb0 = *(const shortx8*)(pb0 + kp); xb1 = *(const shortx8*)(pb1 + kp);
        }
        __syncthreads();
        mfma_step(As, Bs, lane, wm, wn, acc);
        if (k0 + 32 < KD) {
            __syncthreads();
            *(shortx8*)(As + row0 * LST + cole) = ya0;
            *(shortx8*)(As + row1 * LST + cole) = ya1;
            *(shortx8*)(Bs + row0 * LST + cole) = yb0;
            *(shortx8*)(Bs + row1 * LST + cole) = yb1;
            int kq2 = k0 + 96;
            if (kq2 < KD) {
                ya0 = *(const shortx8*)(pa0 + kq2); ya1 = *(const shortx8*)(pa1 + kq2);
                yb0 = *(const shortx8*)(pb0 + kq2); yb1 = *(const shortx8*)(pb1 + kq2);
            }
            __syncthreads();
            mfma_step(As, Bs, lane, wm, wn, acc);
        }
    }
}

// ---- K1: emb fp32 [B,T,C,N] -> x bf16 [B,S,C] ----
__global__ void k_transpose(const float* __restrict__ emb, u16* __restrict__ x) {
    __shared__ u16 tile[32][33];
    int bt = blockIdx.z;
    int c0 = blockIdx.y * 32, n0 = blockIdx.x * 32;
    const float* src = emb + (size_t)bt * Cc * NP;
#pragma unroll
    for (int rr = 0; rr < 32; rr += 8) {
        int c = c0 + threadIdx.y + rr;
        int n = n0 + threadIdx.x;
        u16 v = 0;
        if (n < NP) v = f2bf(src[(size_t)c * NP + n]);
        tile[threadIdx.y + rr][threadIdx.x] = v;
    }
    __syncthreads();
    int b = bt / Tt, t = bt % Tt;
    u16* dst = x + ((size_t)b * Ss + (size_t)t * NP) * Cc;
#pragma unroll
    for (int rr = 0; rr < 32; rr += 8) {
        int n = n0 + threadIdx.y + rr;
        int c = c0 + threadIdx.x;
        if (n < NP) dst[(size_t)n * Cc + c] = tile[threadIdx.x][threadIdx.y + rr];
    }
}

// ---- K2: QKV projections. V written transposed [C,S]. ----
__global__ __launch_bounds__(256) void k_qkv(const u16* __restrict__ x,
                                             const u16* __restrict__ Wall,
                                             u16* __restrict__ Q, u16* __restrict__ Kb,
                                             u16* __restrict__ Vt) {
    __shared__ __align__(16) u16 As[128 * LST], Bs[128 * LST];
    floatx4 acc[4][4];
#pragma unroll
    for (int i = 0; i < 4; ++i)
#pragma unroll
        for (int j = 0; j < 4; ++j) acc[i][j] = (floatx4)(0.f);
    int z = blockIdx.z;
    int qkv = z >> 4, bh = z & 15, b = bh >> 2, h = bh & 3;
    const u16* A = x + (size_t)b * Ss * Cc;
    const u16* W = Wall + (size_t)qkv * Hh * Cc * Cc + (size_t)h * Cc * Cc;
    int mbase = blockIdx.y * 128, nbase = blockIdx.x * 128;
    gemm_bt_core(A, W, Cc, Cc, mbase, Ss - 1, nbase, Cc - 1, Cc, As, Bs, acc);

    int tid = threadIdx.x, lane = tid & 63, wave = tid >> 6, wm = wave >> 1, wn = wave & 1;
    int rq = (lane >> 4) << 2, cn = lane & 15;
    if (qkv < 2) {
        u16* out = (qkv == 0 ? Q : Kb) + (size_t)bh * Ss * Cc;
#pragma unroll
        for (int i = 0; i < 4; ++i) {
            int mb = mbase + wm * 64 + i * 16 + rq;
#pragma unroll
            for (int j = 0; j < 4; ++j) {
                int n = nbase + wn * 64 + j * 16 + cn;
#pragma unroll
                for (int r = 0; r < 4; ++r) {
                    int m = mb + r;
                    if (m < Ss) out[(size_t)m * Cc + n] = f2bf(acc[i][j][r]);
                }
            }
        }
    } else {
        u16* out = Vt + (size_t)bh * Cc * Ss;
#pragma unroll
        for (int i = 0; i < 4; ++i) {
            int m0 = mbase + wm * 64 + i * 16 + rq;
            if (m0 < Ss) {
#pragma unroll
                for (int j = 0; j < 4; ++j) {
                    int n = nbase + wn * 64 + j * 16 + cn;
                    ushort4 v;
                    v.x = f2bf(acc[i][j][0]); v.y = f2bf(acc[i][j][1]);
                    v.z = f2bf(acc[i][j][2]); v.w = f2bf(acc[i][j][3]);
                    *(ushort4*)(out + (size_t)n * Ss + m0) = v;
                }
            }
        }
    }
}

// ---- K3: Sc = (Q K^T)*SCALE_S -> bf16, + fp32 sum/sumsq atomics per (b,h) ----
__global__ __launch_bounds__(256) void k_scores(const u16* __restrict__ Q,
                                                const u16* __restrict__ Kb,
                                                u16* __restrict__ Sc, float* __restrict__ stats) {
    __shared__ __align__(16) u16 As[128 * LST], Bs[128 * LST];
    __shared__ float sred[8];
    floatx4 acc[4][4];
#pragma unroll
    for (int i = 0; i < 4; ++i)
#pragma unroll
        for (int j = 0; j < 4; ++j) acc[i][j] = (floatx4)(0.f);
    int bh = blockIdx.z;
    const u16* A  = Q  + (size_t)bh * Ss * Cc;
    const u16* Bm = Kb + (size_t)bh * Ss * Cc;
    int mbase = blockIdx.y * 128, nbase = blockIdx.x * 128;
    gemm_bt_core(A, Bm, Cc, Cc, mbase, Ss - 1, nbase, Ss - 1, Cc, As, Bs, acc);

    int tid = threadIdx.x, lane = tid & 63, wave = tid >> 6, wm = wave >> 1, wn = wave & 1;
    int rq = (lane >> 4) << 2, cn = lane & 15;
    u16* out = Sc + (size_t)bh * Ss * Ss;
    float lsum = 0.f, lsq = 0.f;
#pragma unroll
    for (int i = 0; i < 4; ++i) {
        int mb = mbase + wm * 64 + i * 16 + rq;
#pragma unroll
        for (int j = 0; j < 4; ++j) {
            int n = nbase + wn * 64 + j * 16 + cn;
            bool nv = n < Ss;
#pragma unroll
            for (int r = 0; r < 4; ++r) {
                int m = mb + r;
                if (nv && m < Ss) {
                    float v = acc[i][j][r] * SCALE_S;
                    out[(size_t)m * Ss + n] = f2bf(v);
                    lsum += v; lsq += v * v;
                }
            }
        }
    }
#pragma unroll
    for (int mk = 1; mk <= 32; mk <<= 1) { lsum += __shfl_xor(lsum, mk); lsq += __shfl_xor(lsq, mk); }
    if (lane == 0) { sred[wave] = lsum; sred[4 + wave] = lsq; }
    __syncthreads();
    if (tid == 0) atomicAdd(&stats[bh * 4 + 0], sred[0] + sred[1] + sred[2] + sred[3]);
    if (tid == 1) atomicAdd(&stats[bh * 4 + 1], sred[4] + sred[5] + sred[6] + sred[7]);
}

// ---- K5: softmax(norm(Sc)) @ V. Block 64x128 (m x n), 4 waves as 2x2,
// wave tile 32x64, acc 2x4 -> 2x total waves (12.5/CU) for latency hiding.
// exp at load; stats inline; head-mean fused (32 atomics/thread). ----
__global__ __launch_bounds__(256) void k_pv(const u16* __restrict__ Sc,
                                            const u16* __restrict__ Vt,
                                            const float* __restrict__ stats,
                                            float* __restrict__ ctxm) {
    __shared__ __align__(16) u16 As[64 * LST], Bs[128 * LST];
    __shared__ float rs[64];
    floatx4 acc[2][4];
#pragma unroll
    for (int i = 0; i < 2; ++i)
#pragma unroll
        for (int j = 0; j < 4; ++j) acc[i][j] = (floatx4)(0.f);
    int bh = blockIdx.z;
    float inv  = 1.f / ((float)Ss * (float)Ss);
    float mean = stats[bh * 4] * inv;
    float var  = fmaxf(stats[bh * 4 + 1] * inv - mean * mean, 0.f);
    float istd = rsqrtf(var + 1e-5f);
    float aa = istd * 1.44269504f;   // log2(e)*istd
    float bb = -mean * aa;
    const u16* A  = Sc + (size_t)bh * Ss * Ss;   // [S][S]
    const u16* Bm = Vt + (size_t)bh * Cc * Ss;   // [C][S]
    int mbase = blockIdx.y * 64;      // 25 m-tiles
    int nbase = blockIdx.x * 128;     // 2 n-tiles
    int tid = threadIdx.x, lane = tid & 63, wave = tid >> 6;
    int wr = wave >> 1, wc = wave & 1;            // 2x2 wave grid over (64,128)
    int rowA = tid >> 2;                          // 0..63
    int cole = (tid & 3) << 3;                    // 0,8,16,24
    int ga = mbase + rowA; ga = ga <= Ss - 1 ? ga : Ss - 1;
    const u16* pa  = A + (size_t)ga * Ss + cole;
    const u16* pb0 = Bm + (size_t)(nbase + rowA) * Ss + cole;
    const u16* pb1 = Bm + (size_t)(nbase + 64 + rowA) * Ss + cole;
    float rsum = 0.f;

    auto ldexp8 = [&](const u16* p) -> shortx8 {
        shortx8 v = *(const shortx8*)(p);
        shortx8 o;
        float s = 0.f;
#pragma unroll
        for (int e = 0; e < 8; ++e) {
            float ex = exp2f(bf2f((u16)v[e]) * aa + bb);
            s += ex; o[e] = (short)f2bf(ex);
        }
        rsum += s;
        return o;
    };

    const int r15 = lane & 15;
    const int kq  = (lane >> 4) << 3;

    shortx8 xa = ldexp8(pa),        ya = ldexp8(pa + 32);
    shortx8 xb0 = *(const shortx8*)(pb0),      xb1 = *(const shortx8*)(pb1);
    shortx8 yb0 = *(const shortx8*)(pb0 + 32), yb1 = *(const shortx8*)(pb1 + 32);

    for (int k0 = 0; k0 < Ss; k0 += 64) {
        __syncthreads();
        *(shortx8*)(As + rowA * LST + cole) = xa;
        *(shortx8*)(Bs + rowA * LST + cole) = xb0;
        *(shortx8*)(Bs + (64 + rowA) * LST + cole) = xb1;
        int kp = k0 + 64;
        if (kp < Ss) {
            xa  = ldexp8(pa + kp);
            xb0 = *(const shortx8*)(pb0 + kp);
            xb1 = *(const shortx8*)(pb1 + kp);
        }
        __syncthreads();
        {
            shortx8 a[2], b[4];
#pragma unroll
            for (int i = 0; i < 2; ++i)
                a[i] = *(const shortx8*)(As + (wr * 32 + i * 16 + r15) * LST + kq);
#pragma unroll
            for (int j = 0; j < 4; ++j)
                b[j] = *(const shortx8*)(Bs + (wc * 64 + j * 16 + r15) * LST + kq);
#pragma unroll
            for (int i = 0; i < 2; ++i)
#pragma unroll
                for (int j = 0; j < 4; ++j)
                    acc[i][j] = __builtin_amdgcn_mfma_f32_16x16x32_bf16(a[i], b[j], acc[i][j], 0, 0, 0);
        }
        if (k0 + 32 < Ss) {
            __syncthreads();
            *(shortx8*)(As + rowA * LST + cole) = ya;
            *(shortx8*)(Bs + rowA * LST + cole) = yb0;
            *(shortx8*)(Bs + (64 + rowA) * LST + cole) = yb1;
            int kq2 = k0 + 96;
            if (kq2 < Ss) {
                ya  = ldexp8(pa + kq2);
                yb0 = *(const shortx8*)(pb0 + kq2);
                yb1 = *(const shortx8*)(pb1 + kq2);
            }
            __syncthreads();
            shortx8 a[2], b[4];
#pragma unroll
            for (int i = 0; i < 2; ++i)
                a[i] = *(const shortx8*)(As + (wr * 32 + i * 16 + r15) * LST + kq);
#pragma unroll
            for (int j = 0; j < 4; ++j)
                b[j] = *(const shortx8*)(Bs + (wc * 64 + j * 16 + r15) * LST + kq);
#pragma unroll
            for (int i = 0; i < 2; ++i)
#pragma unroll
                for (int j = 0; j < 4; ++j)
                    acc[i][j] = __builtin_amdgcn_mfma_f32_16x16x32_bf16(a[i], b[j], acc[i][j], 0, 0, 0);
        }
    }
    // row rowA owned by threads 4r..4r+3 (same wave): reduce over tid&3
    rsum += __shfl_xor(rsum, 1); rsum += __shfl_xor(rsum, 2);
    __syncthreads();
    if ((tid & 3) == 0) rs[rowA] = rsum;
    __syncthreads();

    // fused head-mean: ctxm[b,m,n] += 0.25 * acc / rowsum[m]
    int b = bh >> 2;
    float* outp = ctxm + (size_t)b * Ss * Cc;
    int rq = (lane >> 4) << 2, cn = lane & 15;
#pragma unroll
    for (int i = 0; i < 2; ++i) {
        int ml = wr * 32 + i * 16 + rq;
#pragma unroll
        for (int r = 0; r < 4; ++r) {
            int m = mbase + ml + r;
            if (m < Ss) {
                float invs = 0.25f / rs[ml + r];
#pragma unroll
                for (int j = 0; j < 4; ++j) {
                    int n = nbase + wc * 64 + j * 16 + cn;
                    atomicAdd(&outp[(size_t)m * Cc + n], acc[i][j][r] * invs);
                }
            }
        }
    }
}

// ---- K6: O = ctxm(fp32) @ Wo^T -> fp32 d_out (flat [B,S,C] == [B,T,C,N]) ----
__global__ __launch_bounds__(256) void k_out(const float* __restrict__ ctxm,
                                             const u16* __restrict__ Wo, float* __restrict__ out) {
    __shared__ __align__(16) u16 As[128 * LST], Bs[128 * LST];
    floatx4 acc[4][4];
#pragma unroll
    for (int i = 0; i < 4; ++i)
#pragma unroll
        for (int j = 0; j < 4; ++j) acc[i][j] = (floatx4)(0.f);
    int b = blockIdx.z;
    const float* A = ctxm + (size_t)b * Ss * Cc;
    int mbase = blockIdx.y * 128, nbase = blockIdx.x * 128;
    int tid = threadIdx.x, lane = tid & 63, wave = tid >> 6, wm = wave >> 1, wn = wave & 1;
    int row0 = tid >> 2, row1 = 64 + row0;
    int cole = (tid & 3) << 3;
    int ga0 = mbase + row0; ga0 = ga0 <= Ss - 1 ? ga0 : Ss - 1;
    int ga1 = mbase + row1; ga1 = ga1 <= Ss - 1 ? ga1 : Ss - 1;
    const float* pa0 = A + (size_t)ga0 * Cc + cole;
    const float* pa1 = A + (size_t)ga1 * Cc + cole;
    const u16* pb0 = Wo + (size_t)(nbase + row0 <= Cc - 1 ? nbase + row0 : Cc - 1) * Cc + cole;
    const u16* pb1 = Wo + (size_t)(nbase + row1 <= Cc - 1 ? nbase + row1 : Cc - 1) * Cc + cole;
    float4 a00 = *(const float4*)(pa0), a01 = *(const float4*)(pa0 + 4);
    float4 a10 = *(const float4*)(pa1), a11 = *(const float4*)(pa1 + 4);
    shortx8 vb0 = *(const shortx8*)(pb0);
    shortx8 vb1 = *(const shortx8*)(pb1);
    for (int k0 = 0; k0 < Cc; k0 += 32) {
        shortx8 o0, o1;
        o0[0] = (short)f2bf(a00.x); o0[1] = (short)f2bf(a00.y); o0[2] = (short)f2bf(a00.z); o0[3] = (short)f2bf(a00.w);
        o0[4] = (short)f2bf(a01.x); o0[5] = (short)f2bf(a01.y); o0[6] = (short)f2bf(a01.z); o0[7] = (short)f2bf(a01.w);
        o1[0] = (short)f2bf(a10.x); o1[1] = (short)f2bf(a10.y); o1[2] = (short)f2bf(a10.z); o1[3] = (short)f2bf(a10.w);
        o1[4] = (short)f2bf(a11.x); o1[5] = (short)f2bf(a11.y); o1[6] = (short)f2bf(a11.z); o1[7] = (short)f2bf(a11.w);
        __syncthreads();
        *(shortx8*)(As + row0 * LST + cole) = o0;
        *(shortx8*)(As + row1 * LST + cole) = o1;
        *(shortx8*)(Bs + row0 * LST + cole) = vb0;
        *(shortx8*)(Bs + row1 * LST + cole) = vb1;
        int k1 = k0 + 32;
        if (k1 < Cc) {
            a00 = *(const float4*)(pa0 + k1); a01 = *(const float4*)(pa0 + k1 + 4);
            a10 = *(const float4*)(pa1 + k1); a11 = *(const float4*)(pa1 + k1 + 4);
            vb0 = *(const shortx8*)(pb0 + k1);
            vb1 = *(const shortx8*)(pb1 + k1);
        }
        __syncthreads();
        mfma_step(As, Bs, lane, wm, wn, acc);
    }
    int rq = (lane >> 4) << 2, cn = lane & 15;
    float* o = out + (size_t)b * Ss * Cc;
#pragma unroll
    for (int i = 0; i < 4; ++i) {
        int mb = mbase + wm * 64 + i * 16 + rq;
#pragma unroll
        for (int j = 0; j < 4; ++j) {
            int n = nbase + wn * 64 + j * 16 + cn;
#pragma unroll
            for (int r = 0; r < 4; ++r) {
                int m = mb + r;
                if (m < Ss) o[(size_t)m * Cc + n] = acc[i][j][r];   // fp32 store
            }
        }
    }
}

extern "C" void kernel_launch(void* const* d_in, const int* in_sizes, int n_in,
                              void* d_out, int out_size, void* d_ws, size_t ws_size,
                              hipStream_t stream) {
    const float* emb = (const float*)d_in[0];
    float* out = (float*)d_out;

    char* ws = (char*)d_ws;
    size_t off = 0;
    auto alloc = [&](size_t bytes) -> void* {
        void* p = ws + off;
        off = (off + bytes + 255) & ~(size_t)255;
        return p;
    };
    // Total ~122.6 MiB
    float* stats = (float*)alloc(16 * 4 * sizeof(float));
    u16* Wall = (u16*)alloc((size_t)(3 * Hh + 1) * Cc * Cc * 2);  // [Wq|Wk|Wv|Wo]
    u16* x    = (u16*)alloc((size_t)Bb * Ss * Cc * 2);            // 3.1 MiB
    u16* Q    = (u16*)alloc((size_t)Bb * Hh * Ss * Cc * 2);       // 12.25 MiB
    u16* Kb   = (u16*)alloc((size_t)Bb * Hh * Ss * Cc * 2);       // 12.25 MiB
    u16* Vt   = (u16*)alloc((size_t)Bb * Hh * Ss * Cc * 2);       // 12.25 MiB ([C,S])
    float* ctxm = (float*)alloc((size_t)Bb * Ss * Cc * 4);        // 6.1 MiB fp32 head-mean accum
    u16* Sc   = (u16*)alloc((size_t)Bb * Hh * Ss * Ss * 2);       // 75.0 MiB
    u16* Woc  = Wall + (size_t)3 * Hh * Cc * Cc;

    hipMemsetAsync(stats, 0, 16 * 4 * sizeof(float), stream);
    hipMemsetAsync(ctxm, 0, (size_t)Bb * Ss * Cc * 4, stream);

    k_convall<<<dim3(3328), dim3(256), 0, stream>>>((const float*)d_in[1], (const float*)d_in[2],
                                                    (const float*)d_in[3], (const float*)d_in[4], Wall);
    k_transpose<<<dim3(7, 8, 32), dim3(32, 8), 0, stream>>>(emb, x);
    k_qkv<<<dim3(2, 13, 48), dim3(256), 0, stream>>>(x, Wall, Q, Kb, Vt);
    k_scores<<<dim3(13, 13, 16), dim3(256), 0, stream>>>(Q, Kb, Sc, stats);
    k_pv<<<dim3(2, 25, 16), dim3(256), 0, stream>>>(Sc, Vt, stats, ctxm);
    k_out<<<dim3(2, 13, 4), dim3(256), 0, stream>>>(ctxm, Woc, out);
}